// Round 12
// baseline (1292.368 us; speedup 1.0000x reference)
//
#include <hip/hip_runtime.h>

typedef unsigned short u16;
typedef unsigned int   u32;
typedef __attribute__((ext_vector_type(2))) float f32x2;
typedef __attribute__((ext_vector_type(4))) float f32x4;
typedef __attribute__((ext_vector_type(8))) u16   u16x8;
typedef __attribute__((ext_vector_type(4))) u16   u16x4;
typedef __attribute__((ext_vector_type(4))) u32   u32x4;

// ---------------- helpers ----------------
__device__ __forceinline__ u16 f2bf(float x) {
  u32 u = __builtin_bit_cast(u32, x);
  u = (u + 0x7fffu + ((u >> 16) & 1u)) >> 16;
  return (u16)u;
}
__device__ __forceinline__ float bf2f(u16 h) {
  return __builtin_bit_cast(float, (u32)h << 16);
}
__device__ __forceinline__ float fast_sig(float x) { return 1.f / (1.f + __expf(-x)); }
__device__ __forceinline__ float fast_tanh(float x) {
  float e = __expf(2.f * x);
  return 1.f - 2.f / (e + 1.f);
}

__device__ __forceinline__ f32x4 mfma_bf16(u16x8 a, u16x8 b, f32x4 c) {
  asm volatile("v_mfma_f32_16x16x32_bf16 %0, %1, %2, %0" : "+v"(c) : "v"(a), "v"(b));
  return c;
}

__device__ __forceinline__ void gload_lds16(const void* g, void* l) {
  __builtin_amdgcn_global_load_lds(
      (__attribute__((address_space(1))) u32*)g,
      (__attribute__((address_space(3))) u32*)l, 16, 0, 0);
}

// ---------------- fused prep ----------------
__device__ __forceinline__ void conv4(const float* __restrict__ s, u16* __restrict__ d, int i) {
  f32x4 v = *(const f32x4*)(s + i);
  u16x4 o;
  o.x = f2bf(v.x); o.y = f2bf(v.y); o.z = f2bf(v.z); o.w = f2bf(v.w);
  *(u16x4*)(d + i) = o;
}

__global__ __launch_bounds__(256) void k_prep(
    const float* __restrict__ batch_H, const float* __restrict__ W_i2h,
    const float* __restrict__ emb, const float* __restrict__ W_ih,
    const float* __restrict__ W_h2h, const float* __restrict__ W_hh,
    const float* __restrict__ W_gen, const float* __restrict__ b_ih,
    const float* __restrict__ b_hh,
    u16* __restrict__ bHb, u16* __restrict__ Wi2hb, u16* __restrict__ embb,
    u16* __restrict__ Wctxb, u16* __restrict__ Wceb, u16* __restrict__ Whcatb,
    u16* __restrict__ Wgenb, float* __restrict__ biascat, u16* __restrict__ WTb,
    u16* __restrict__ hb, float* __restrict__ cst) {
  const u32 u = blockIdx.x * 256 + threadIdx.x;
  if (u < 2097152u) { conv4(batch_H, bHb, u * 4); return; }
  if (u < 2162688u) { conv4(W_i2h, Wi2hb, (u - 2097152u) * 4); return; }
  if (u < 2586624u) { conv4(emb, embb, (u - 2162688u) * 4); return; }
  if (u < 2588672u) {  // zero emb pad rows 6624..6655
    *(u16x4*)(embb + 1695744u + (u - 2586624u) * 4) = (u16x4){0, 0, 0, 0};
    return;
  }
  if (u < 2850816u) {  // Wctx = W_ih[:, 0:512]
    int i = (u - 2588672u) * 4;
    int r = i >> 9, c = i & 511;
    f32x4 v = *(const f32x4*)(W_ih + (size_t)r * 768 + c);
    u16x4 o;
    o.x = f2bf(v.x); o.y = f2bf(v.y); o.z = f2bf(v.z); o.w = f2bf(v.w);
    *(u16x4*)(Wctxb + i) = o;
    return;
  }
  if (u < 2981888u) {  // Wce = W_ih[:, 512:768]
    int i = (u - 2850816u) * 4;
    int r = i >> 8, c = i & 255;
    f32x4 v = *(const f32x4*)(W_ih + (size_t)r * 768 + 512 + c);
    u16x4 o;
    o.x = f2bf(v.x); o.y = f2bf(v.y); o.z = f2bf(v.z); o.w = f2bf(v.w);
    *(u16x4*)(Wceb + i) = o;
    return;
  }
  if (u < 3309568u) {  // Whcat = [W_h2h ; W_hh], 2560 x 512
    int i = (u - 2981888u) * 4;
    int r = i >> 9, c = i & 511;
    const float* src = (r < 512) ? (W_h2h + (size_t)r * 512 + c)
                                 : (W_hh + (size_t)(r - 512) * 512 + c);
    f32x4 v = *(const f32x4*)src;
    u16x4 o;
    o.x = f2bf(v.x); o.y = f2bf(v.y); o.z = f2bf(v.z); o.w = f2bf(v.w);
    *(u16x4*)(Whcatb + i) = o;
    return;
  }
  if (u < 4161536u) {  // Wgen padded to 6656 rows
    int i = (u - 3309568u) * 4;
    int r = i >> 9;
    if (r < 6624) conv4(W_gen, Wgenb, i);
    else *(u16x4*)(Wgenb + i) = (u16x4){0, 0, 0, 0};
    return;
  }
  if (u < 4162048u) {  // biascat
    int j = (u - 4161536u) * 4;
    f32x4 a = *(const f32x4*)(b_ih + j), b = *(const f32x4*)(b_hh + j);
    f32x4 r = {a.x + b.x, a.y + b.y, a.z + b.z, a.w + b.w};
    *(f32x4*)(biascat + j) = r;
    return;
  }
  if (u < 4227584u) {  // WT[k][j] = W_h2h[j][k] (k-major, for the in-block hp GEMV)
    int i = (u - 4162048u) * 4;
    int k = i >> 9, j = i & 511;
    u16x4 o;
#pragma unroll
    for (int q = 0; q < 4; ++q) o[q] = f2bf(W_h2h[(size_t)(j + q) * 512 + k]);
    *(u16x4*)(WTb + i) = o;
    return;
  }
  if (u < 4243968u) {  // zero hb (h0 = 0), 16B units
    *(u32x4*)((char*)hb + (size_t)(u - 4227584u) * 16) = (u32x4){0, 0, 0, 0};
    return;
  }
  if (u < 4276736u) {  // zero cst
    *(u32x4*)((char*)cst + (size_t)(u - 4243968u) * 16) = (u32x4){0, 0, 0, 0};
    return;
  }
}

// ---------------- 128x128x(BK=128) GEMM body: C = A * B^T (+bias) ----------------
// OUT_MODE: 1 = f32 + bias, 2 = bf16 no bias, 3 = bf16 + bias. 4 waves of 64x64.
template <int OUT_MODE>
__device__ __forceinline__ void gemm128_body(
    const u16* __restrict__ A, int lda, const u16* __restrict__ B, int ldb,
    const float* __restrict__ bias, float* __restrict__ Cf, u16* __restrict__ Cb,
    int ldc, int Nreal, int K, int m0, int n0, char* smem) {
  u16* sA = (u16*)smem;            // 128 x 128 = 32 KB
  u16* sB = (u16*)(smem + 32768);  // 128 x 128 = 32 KB
  const int tid = threadIdx.x;
  const int lane = tid & 63, wave = tid >> 6;
  const int wr = wave >> 1, wc = wave & 1;
  const int l15 = lane & 15, lhi = lane >> 4;

  f32x4 acc[4][4];
#pragma unroll
  for (int i = 0; i < 4; ++i)
#pragma unroll
    for (int j = 0; j < 4; ++j) acc[i][j] = 0.f;

  for (int k0 = 0; k0 < K; k0 += 128) {
    __syncthreads();
#pragma unroll
    for (int j = 0; j < 8; ++j) {  // A: 128 rows x 16 chunks
      int idx = j * 256 + tid, row = idx >> 4, cc = idx & 15, c = cc ^ (row & 15);
      gload_lds16(A + (size_t)(m0 + row) * lda + (k0 + c * 8), sA + idx * 8);
    }
#pragma unroll
    for (int j = 0; j < 8; ++j) {  // B: 128 rows x 16 chunks
      int idx = j * 256 + tid, row = idx >> 4, cc = idx & 15, c = cc ^ (row & 15);
      gload_lds16(B + (size_t)(n0 + row) * ldb + (k0 + c * 8), sB + idx * 8);
    }
    __syncthreads();

#pragma unroll
    for (int ks = 0; ks < 4; ++ks) {
      u16x8 av[4], bv[4];
#pragma unroll
      for (int mi = 0; mi < 4; ++mi) {
        int row = wr * 64 + mi * 16 + l15;
        int ch = row * 16 + ((ks * 4 + lhi) ^ (row & 15));
        av[mi] = *(const u16x8*)(sA + ch * 8);
      }
#pragma unroll
      for (int ni = 0; ni < 4; ++ni) {
        int row = wc * 64 + ni * 16 + l15;
        int ch = row * 16 + ((ks * 4 + lhi) ^ (row & 15));
        bv[ni] = *(const u16x8*)(sB + ch * 8);
      }
#pragma unroll
      for (int mi = 0; mi < 4; ++mi)
#pragma unroll
        for (int ni = 0; ni < 4; ++ni) acc[mi][ni] = mfma_bf16(av[mi], bv[ni], acc[mi][ni]);
    }
  }

  asm volatile("s_nop 7\ns_nop 7\ns_nop 7");  // MFMA->VALU hazard guard

#pragma unroll
  for (int mi = 0; mi < 4; ++mi) {
#pragma unroll
    for (int ni = 0; ni < 4; ++ni) {
      int col = n0 + wc * 64 + ni * 16 + l15;
      if (col < Nreal) {
        float bvv = (OUT_MODE == 1 || OUT_MODE == 3) ? bias[col] : 0.f;
#pragma unroll
        for (int r = 0; r < 4; ++r) {
          int row = m0 + wr * 64 + mi * 16 + lhi * 4 + r;
          float v = acc[mi][ni][r] + bvv;
          if (OUT_MODE == 2 || OUT_MODE == 3)
            Cb[(size_t)row * ldc + col] = f2bf(v);
          else
            Cf[(size_t)row * ldc + col] = v;
        }
      }
    }
  }
}

// SWZ: bijective XCD-aware remap (requires gridX*gridY % 8 == 0)
template <int OUT_MODE, bool SWZ>
__global__ __launch_bounds__(256) void kGemm128(const u16* __restrict__ A, int lda,
                                                const u16* __restrict__ B, int ldb,
                                                const float* __restrict__ bias,
                                                float* __restrict__ Cf, u16* __restrict__ Cb,
                                                int ldc, int Nreal, int K) {
  __shared__ __align__(16) char smem[65536];
  int bx = blockIdx.x, by = blockIdx.y;
  if (SWZ) {
    int gx = gridDim.x;
    int lin = by * gx + bx;
    int q = (gx * gridDim.y) >> 3;
    int idx = (lin & 7) * q + (lin >> 3);
    by = idx / gx;
    bx = idx - by * gx;
  }
  gemm128_body<OUT_MODE>(A, lda, B, ldb, bias, Cf, Cb, ldc, Nreal, K,
                         by * 128, bx * 128, smem);
}

// ---------------- kHE: Hproj GEMM + E2G GEMM (bf16 out) in one dispatch ----------------
__global__ __launch_bounds__(256) void kHE(const u16* __restrict__ bHb,
                                           const u16* __restrict__ Wi2hb,
                                           u16* __restrict__ Hproj,
                                           const u16* __restrict__ embb,
                                           const u16* __restrict__ Wceb,
                                           const float* __restrict__ biascat,
                                           u16* __restrict__ E2Gb) {
  __shared__ __align__(16) char smem[65536];
  const int bid = blockIdx.x;
  if (bid < 512) {  // Hproj: M=16384 (128 mt) x N=512 (4 nt), K=512
    gemm128_body<2>(bHb, 512, Wi2hb, 512, nullptr, nullptr, Hproj, 512, 512, 512,
                    (bid >> 2) * 128, (bid & 3) * 128, smem);
  } else {  // E2G: M=6656 (52 mt) x N=2048 (16 nt), K=256 -> bf16 + bias
    int r = bid - 512;
    gemm128_body<3>(embb, 256, Wceb, 256, biascat, nullptr, E2Gb, 2048, 2048, 256,
                    (r >> 4) * 128, (r & 15) * 128, smem);
  }
}

// ---------------- kBA: fused {attention(b-pair) + inline hp GEMV} | {gh GEMM} ----------------
// grid 256 (1/CU):
//  blocks 0..127  : attention for b = 2*bid, 2*bid+1. hp computed in-block via
//                   k-major WT GEMV (W_h2h L2-resident, coalesced u32 reads).
//  blocks 128..255: gh = h @ W_hh^T tile (BM=64, BN=64, single-stage full-K).
// At step 0 (h=0) this yields hp = b_h2h and gh = 0 — no special case.
__global__ __launch_bounds__(256) void kBA(const u16* __restrict__ hb,
                                           const u16* __restrict__ WTb,
                                           const u16* __restrict__ Whcatb,
                                           const float* __restrict__ b_h2h,
                                           const float* __restrict__ wsc,
                                           const u16* __restrict__ Hproj,
                                           const u16* __restrict__ bh,
                                           u16* __restrict__ ctxb,
                                           float* __restrict__ ghbuf) {
  extern __shared__ __align__(16) char smem[];
  const int tid = threadIdx.x;
  const int bid = blockIdx.x;

  if (bid >= 128) {  // ---- gh GEMM tile (single-stage full-K, 128 KB LDS) ----
    u16* sA = (u16*)smem;             // 64 x 512 = 64 KB
    u16* sB = (u16*)(smem + 65536);   // 64 x 512 = 64 KB
    const int r = bid - 128;
    const int b0 = (r >> 5) * 64;           // 4 batch tiles
    const int n0 = 512 + (r & 31) * 64;     // 32 gh column tiles (Whcat rows 512..2559)
    const int lane = tid & 63, wave = tid >> 6;
    const int l15 = lane & 15, lhi = lane >> 4;
#pragma unroll
    for (int j = 0; j < 16; ++j) {  // A: 64 rows x 64 chunks
      int idx = j * 256 + tid, row = idx >> 6, cc = idx & 63, c = cc ^ (row & 15);
      gload_lds16(hb + (size_t)(b0 + row) * 512 + c * 8, sA + idx * 8);
    }
#pragma unroll
    for (int j = 0; j < 16; ++j) {  // B: 64 rows x 64 chunks
      int idx = j * 256 + tid, row = idx >> 6, cc = idx & 63, c = cc ^ (row & 15);
      gload_lds16(Whcatb + (size_t)(n0 + row) * 512 + c * 8, sB + idx * 8);
    }
    __syncthreads();  // single vmcnt drain

    f32x4 acc[4];
#pragma unroll
    for (int j = 0; j < 4; ++j) acc[j] = 0.f;
#pragma unroll
    for (int ks = 0; ks < 16; ++ks) {
      u16x8 av, bv[4];
      {
        int row = wave * 16 + l15;
        int ch = row * 64 + ((ks * 4 + lhi) ^ (row & 15));
        av = *(const u16x8*)(sA + ch * 8);
      }
#pragma unroll
      for (int ni = 0; ni < 4; ++ni) {
        int row = ni * 16 + l15;
        int ch = row * 64 + ((ks * 4 + lhi) ^ (row & 15));
        bv[ni] = *(const u16x8*)(sB + ch * 8);
      }
#pragma unroll
      for (int ni = 0; ni < 4; ++ni) acc[ni] = mfma_bf16(av, bv[ni], acc[ni]);
    }
    asm volatile("s_nop 7\ns_nop 7\ns_nop 7");
#pragma unroll
    for (int ni = 0; ni < 4; ++ni) {
      int col = n0 + ni * 16 + l15 - 512;
      int rowg = b0 + wave * 16 + lhi * 4;
#pragma unroll
      for (int rr = 0; rr < 4; ++rr)
        ghbuf[(size_t)(rowg + rr) * 2048 + col] = acc[ni][rr];
    }
    return;
  }

  // ---- attention path: b-pair (b = 2*bid + bb) ----
  float* hsm  = (float*)smem;                  // [2][512]
  float* hpsp = (float*)(smem + 4096);         // [2][528] padded j -> j + (j>>5)
  float* wssp = (float*)(smem + 8448);         // [528]
  float* es   = (float*)(smem + 10560);        // [2][64]
  const int b0 = bid * 2;

  {  // load h (both b) -> f32 LDS; w_score padded
    int bb = tid >> 7, off = (tid & 127) * 4;
    u16x4 hv = *(const u16x4*)(hb + (size_t)(b0 + bb) * 512 + off);
#pragma unroll
    for (int q = 0; q < 4; ++q) hsm[bb * 512 + off + q] = bf2f(hv[q]);
    int j0 = tid * 2;
    int pi = j0 + (j0 >> 5);
    wssp[pi] = wsc[j0];
    wssp[pi + 1] = wsc[j0 + 1];
  }
  __syncthreads();

  {  // hp GEMV: thread owns j-pair (2*tid, 2*tid+1), both b's; WT k-major coalesced
    float a00 = 0.f, a01 = 0.f, a10 = 0.f, a11 = 0.f;
    const u16* wp = WTb + tid * 2;
#pragma unroll 8
    for (int k = 0; k < 512; ++k) {
      u32 ww = *(const u32*)(wp + (size_t)k * 512);
      float f0 = bf2f((u16)(ww & 0xffffu)), f1 = bf2f((u16)(ww >> 16));
      float h0 = hsm[k], h1 = hsm[512 + k];
      a00 = fmaf(h0, f0, a00); a01 = fmaf(h0, f1, a01);
      a10 = fmaf(h1, f0, a10); a11 = fmaf(h1, f1, a11);
    }
    int j0 = tid * 2, j1 = j0 + 1;
    float bz0 = b_h2h[j0], bz1 = b_h2h[j1];
    int p0 = j0 + (j0 >> 5), p1 = j1 + (j1 >> 5);
    hpsp[p0] = a00 + bz0;
    hpsp[p1] = a01 + bz1;
    hpsp[528 + p0] = a10 + bz0;
    hpsp[528 + p1] = a11 + bz1;
  }
  __syncthreads();

  // scores: 128 threads per b. ch16 = h-chunk, 8 t-rows per tg iter.
  const int bb = tid >> 7, tid7 = tid & 127;
  const int b = b0 + bb;
  const int ch16 = tid7 & 15, trow = tid7 >> 4;
  const int hbase = ch16 * 33;
  const int hc = ch16 * 32;
  {
    const float* hps = hpsp + bb * 528;
    float hpr[32], wsr[32];
#pragma unroll
    for (int j = 0; j < 32; ++j) {
      hpr[j] = hps[hbase + j];
      wsr[j] = wssp[hbase + j];
    }
#pragma unroll
    for (int tg = 0; tg < 8; ++tg) {
      int t = tg * 8 + trow;
      const u16* hr = Hproj + (size_t)(b * 64 + t) * 512 + hc;
      float s = 0.f;
#pragma unroll
      for (int jo = 0; jo < 32; jo += 8) {
        u16x8 hv = *(const u16x8*)(hr + jo);
#pragma unroll
        for (int j = 0; j < 8; ++j) {
          float x = bf2f(hv[j]) + hpr[jo + j];
          s += fast_tanh(x) * wsr[jo + j];
        }
      }
#pragma unroll
      for (int off = 8; off; off >>= 1) s += __shfl_xor(s, off, 16);
      if (ch16 == 0) es[bb * 64 + t] = s;
    }
  }
  __syncthreads();
  {  // softmax over t: wave 0 -> b0, wave 2 -> b1
    int wv = tid >> 6;
    if ((wv & 1) == 0) {
      int sb = wv >> 1, lane = tid & 63;
      float v = es[sb * 64 + lane];
      float m = v;
#pragma unroll
      for (int o = 32; o; o >>= 1) m = fmaxf(m, __shfl_xor(m, o, 64));
      float p = __expf(v - m);
      float su = p;
#pragma unroll
      for (int o = 32; o; o >>= 1) su += __shfl_xor(su, o, 64);
      es[sb * 64 + lane] = p / su;
    }
  }
  __syncthreads();
  {  // context: 128 threads per b, 4 d's each
    const int d0 = tid7 * 4;
    const u16* base = bh + (size_t)b * 32768 + d0;
    float c0 = 0.f, c1 = 0.f, c2 = 0.f, c3 = 0.f;
#pragma unroll 8
    for (int t = 0; t < 64; ++t) {
      u32 w0 = *(const u32*)(base + t * 512);
      u32 w1 = *(const u32*)(base + t * 512 + 2);
      float a = es[bb * 64 + t];
      c0 = fmaf(a, bf2f((u16)(w0 & 0xffffu)), c0);
      c1 = fmaf(a, bf2f((u16)(w0 >> 16)), c1);
      c2 = fmaf(a, bf2f((u16)(w1 & 0xffffu)), c2);
      c3 = fmaf(a, bf2f((u16)(w1 >> 16)), c3);
    }
    u16x4 pk;
    pk.x = f2bf(c0); pk.y = f2bf(c1); pk.z = f2bf(c2); pk.w = f2bf(c3);
    *(u16x4*)(ctxb + (size_t)b * 512 + d0) = pk;
  }
}

// ---------------- kC: gates_ctx GEMM single-stage full-K + gh + E2G + LSTM ----------------
// grid (32, 8): jj = 16-wide j-tile (4 gate segs -> 64 B-rows), b0 = 32-wide batch tile.
__global__ __launch_bounds__(256) void kC_gates_lstm(const u16* __restrict__ ctxb,
                                                     const u16* __restrict__ Wctxb,
                                                     const u16* __restrict__ E2Gb,
                                                     const float* __restrict__ ghbuf,
                                                     const int* __restrict__ text,
                                                     float* __restrict__ cst,
                                                     u16* __restrict__ hb,
                                                     u16* __restrict__ hsb, int step) {
  extern __shared__ __align__(16) char smem[];
  u16* sA = (u16*)smem;             // 32 x 512 = 32 KB
  u16* sB = (u16*)(smem + 32768);   // 64 x 512 = 64 KB
  const int tid = threadIdx.x;
  const int lane = tid & 63, wave = tid >> 6;
  const int wr = wave >> 1, wc = wave & 1;  // WM=16 (2 m-waves), WN=32 (2 n-waves)
  const int l15 = lane & 15, lhi = lane >> 4;
  const int jj = blockIdx.x;       // 0..31, 16 j's each
  const int b0 = blockIdx.y * 32;  // 0..7

#pragma unroll
  for (int j = 0; j < 8; ++j) {  // A: 32 rows x 64 chunks
    int idx = j * 256 + tid, row = idx >> 6, cc = idx & 63, c = cc ^ (row & 15);
    gload_lds16(ctxb + (size_t)(b0 + row) * 512 + c * 8, sA + idx * 8);
  }
#pragma unroll
  for (int j = 0; j < 16; ++j) {  // B: 64 rows (4 segs x 16 j) x 64 chunks
    int idx = j * 256 + tid, row = idx >> 6, cc = idx & 63, c = cc ^ (row & 15);
    int grow = (row >> 4) * 512 + jj * 16 + (row & 15);
    gload_lds16(Wctxb + (size_t)grow * 512 + c * 8, sB + idx * 8);
  }
  __syncthreads();  // single vmcnt drain

  f32x4 acc[2];
#pragma unroll
  for (int j = 0; j < 2; ++j) acc[j] = 0.f;
#pragma unroll
  for (int ks = 0; ks < 16; ++ks) {
    u16x8 av, bv[2];
    {
      int row = wr * 16 + l15;
      int ch = row * 64 + ((ks * 4 + lhi) ^ (row & 15));
      av = *(const u16x8*)(sA + ch * 8);
    }
#pragma unroll
    for (int ni = 0; ni < 2; ++ni) {
      int row = wc * 32 + ni * 16 + l15;
      int ch = row * 64 + ((ks * 4 + lhi) ^ (row & 15));
      bv[ni] = *(const u16x8*)(sB + ch * 8);
    }
#pragma unroll
    for (int ni = 0; ni < 2; ++ni) acc[ni] = mfma_bf16(av, bv[ni], acc[ni]);
  }

  asm volatile("s_nop 7\ns_nop 7\ns_nop 7");  // MFMA->VALU hazard guard
  __syncthreads();                            // staging reads done -> reuse LDS
  float (*gsm)[68] = (float(*)[68])smem;      // 32 x 68 f32 = 8.7 KB
#pragma unroll
  for (int ni = 0; ni < 2; ++ni) {
    int col = wc * 32 + ni * 16 + l15;  // col: seg = col>>4, jloc = col&15
    int row = wr * 16 + lhi * 4;
#pragma unroll
    for (int r = 0; r < 4; ++r) gsm[row + r][col] = acc[ni][r];
  }
  __syncthreads();

  {  // LSTM: thread owns bl = tid>>3 (32 b's), 2 j's at jl = (tid&7)*2
    const int bl = tid >> 3, jl = (tid & 7) * 2;
    const int b = b0 + bl;
    const int jg = jj * 16 + jl;  // global j base (2 consecutive)
    const int ci = text[b * 26 + step];
    const float* gh = ghbuf + (size_t)b * 2048;
    const u16* ge = E2Gb + (size_t)ci * 2048;  // bf16, includes biascat
    float cn[2];
    u16 hbv[2];
#pragma unroll
    for (int q = 0; q < 2; ++q) {
      int jc = jl + q, j = jg + q;
      float gi = gsm[bl][jc]      + gh[j]        + bf2f(ge[j]);
      float gf = gsm[bl][16 + jc] + gh[512 + j]  + bf2f(ge[512 + j]);
      float gg = gsm[bl][32 + jc] + gh[1024 + j] + bf2f(ge[1024 + j]);
      float go = gsm[bl][48 + jc] + gh[1536 + j] + bf2f(ge[1536 + j]);
      float c = fast_sig(gf) * cst[(size_t)b * 512 + j] + fast_sig(gi) * fast_tanh(gg);
      cn[q] = c;
      hbv[q] = f2bf(fast_sig(go) * fast_tanh(c));
    }
    *(f32x2*)(cst + (size_t)b * 512 + jg) = *(f32x2*)cn;
    u32 pk = (u32)hbv[0] | ((u32)hbv[1] << 16);
    *(u32*)(hb + (size_t)b * 512 + jg) = pk;
    *(u32*)(hsb + (size_t)(b * 26 + step) * 512 + jg) = pk;
  }
}

// ---------------- launch ----------------
extern "C" void kernel_launch(void* const* d_in, const int* in_sizes, int n_in,
                              void* d_out, int out_size, void* d_ws, size_t ws_size,
                              hipStream_t stream) {
  const float* batch_H = (const float*)d_in[0];
  const int*   text    = (const int*)d_in[1];
  const float* W_i2h   = (const float*)d_in[2];
  const float* W_h2h   = (const float*)d_in[3];
  const float* b_h2h   = (const float*)d_in[4];
  const float* w_score = (const float*)d_in[5];
  const float* W_ih    = (const float*)d_in[6];
  const float* W_hh    = (const float*)d_in[7];
  const float* b_ih    = (const float*)d_in[8];
  const float* b_hh    = (const float*)d_in[9];
  const float* emb     = (const float*)d_in[10];
  const float* W_gen   = (const float*)d_in[11];
  const float* b_gen   = (const float*)d_in[12];
  float* out = (float*)d_out;

  // allow large dynamic LDS for the fused step kernels (host-side, capture-safe)
  static bool attr_done = []() {
    hipFuncSetAttribute(reinterpret_cast<const void*>(kBA),
                        hipFuncAttributeMaxDynamicSharedMemorySize, 131072);
    hipFuncSetAttribute(reinterpret_cast<const void*>(kC_gates_lstm),
                        hipFuncAttributeMaxDynamicSharedMemorySize, 98304);
    return true;
  }();
  (void)attr_done;

  // Big bf16 scratch at the front of d_out (fully overwritten by the final GEMM,
  // which reads only hsb/Wgenb; both live in d_ws).
  u16* bHb   = (u16*)d_out;          // 16 MB
  u16* Hproj = bHb + 8388608;        // 16 MB

  char* w = (char*)d_ws;
  auto alloc = [&](size_t bytes) {
    char* p = w;
    w += (bytes + 255) & ~(size_t)255;
    return p;
  };
  u16*   Wi2hb   = (u16*)alloc(512ull * 512 * 2);
  u16*   Whcatb  = (u16*)alloc(2560ull * 512 * 2);   // [W_h2h ; W_hh]
  u16*   Wctxb   = (u16*)alloc(2048ull * 512 * 2);   // W_ih[:, 0:512]
  u16*   Wceb    = (u16*)alloc(2048ull * 256 * 2);   // W_ih[:, 512:768]
  u16*   Wgenb   = (u16*)alloc(6656ull * 512 * 2);
  u16*   embb    = (u16*)alloc(6656ull * 256 * 2);   // padded rows >= 6624
  float* biascat = (float*)alloc(2048ull * 4);
  u16*   WTb     = (u16*)alloc(512ull * 512 * 2);    // W_h2h^T, k-major
  u16*   ctxb    = (u16*)alloc(256ull * 512 * 2);
  u16*   hb      = (u16*)alloc(256ull * 512 * 2);
  float* cst     = (float*)alloc(256ull * 512 * 4);
  float* ghbuf   = (float*)alloc(256ull * 2048 * 4);
  u16*   hsb     = (u16*)alloc(6656ull * 512 * 2);
  u16*   E2Gb    = (u16*)alloc(6656ull * 2048 * 2);  // bf16: emb@W_ce^T + biascat

  // 1) fused prep (conversions + packing + WT transpose + zero h/c)
  k_prep<<<16706, 256, 0, stream>>>(batch_H, W_i2h, emb, W_ih, W_h2h, W_hh, W_gen,
                                    b_ih, b_hh, bHb, Wi2hb, embb, Wctxb, Wceb,
                                    Whcatb, Wgenb, biascat, WTb, hb, cst);

  // 2) Hproj + E2G (bf16) in one dispatch
  kHE<<<1344, 256, 0, stream>>>(bHb, Wi2hb, Hproj, embb, Wceb, biascat, E2Gb);

  // 3) recurrence: 2 dispatches per step
  //    kBA = attention (inline hp GEMV) + gh GEMM;  kC = gates + LSTM
  for (int s = 0; s < 26; ++s) {
    kBA<<<256, 256, 131072, stream>>>(hb, WTb, Whcatb, b_h2h, w_score, Hproj, bHb,
                                      ctxb, ghbuf);
    kC_gates_lstm<<<dim3(32, 8), 256, 98304, stream>>>(ctxb, Wctxb, E2Gb, ghbuf, text,
                                                       cst, hb, hsb, s);
  }

  // 4) probs = hs @ W_gen^T + b_gen -> f32 out (M=6656, N=6624, K=512), XCD-swizzled
  kGemm128<1, true><<<dim3(52, 52), 256, 0, stream>>>(
      hsb, 512, Wgenb, 512, b_gen, out, nullptr, 6624, 6624, 512);

  (void)in_sizes; (void)n_in; (void)out_size; (void)ws_size;
}

// Round 13
// 762.886 us; speedup vs baseline: 1.6941x; 1.6941x over previous
//
#include <hip/hip_runtime.h>

typedef unsigned short u16;
typedef unsigned int   u32;
typedef __attribute__((ext_vector_type(2))) float f32x2;
typedef __attribute__((ext_vector_type(4))) float f32x4;
typedef __attribute__((ext_vector_type(8))) u16   u16x8;
typedef __attribute__((ext_vector_type(4))) u16   u16x4;
typedef __attribute__((ext_vector_type(4))) u32   u32x4;

// ---------------- helpers ----------------
__device__ __forceinline__ u16 f2bf(float x) {
  u32 u = __builtin_bit_cast(u32, x);
  u = (u + 0x7fffu + ((u >> 16) & 1u)) >> 16;
  return (u16)u;
}
__device__ __forceinline__ float bf2f(u16 h) {
  return __builtin_bit_cast(float, (u32)h << 16);
}
__device__ __forceinline__ float fast_sig(float x) { return 1.f / (1.f + __expf(-x)); }
__device__ __forceinline__ float fast_tanh(float x) {
  float e = __expf(2.f * x);
  return 1.f - 2.f / (e + 1.f);
}

__device__ __forceinline__ f32x4 mfma_bf16(u16x8 a, u16x8 b, f32x4 c) {
  asm volatile("v_mfma_f32_16x16x32_bf16 %0, %1, %2, %0" : "+v"(c) : "v"(a), "v"(b));
  return c;
}

__device__ __forceinline__ void gload_lds16(const void* g, void* l) {
  __builtin_amdgcn_global_load_lds(
      (__attribute__((address_space(1))) u32*)g,
      (__attribute__((address_space(3))) u32*)l, 16, 0, 0);
}

// ---------------- fused prep ----------------
__device__ __forceinline__ void conv4(const float* __restrict__ s, u16* __restrict__ d, int i) {
  f32x4 v = *(const f32x4*)(s + i);
  u16x4 o;
  o.x = f2bf(v.x); o.y = f2bf(v.y); o.z = f2bf(v.z); o.w = f2bf(v.w);
  *(u16x4*)(d + i) = o;
}

__global__ __launch_bounds__(256) void k_prep(
    const float* __restrict__ batch_H, const float* __restrict__ W_i2h,
    const float* __restrict__ emb, const float* __restrict__ W_ih,
    const float* __restrict__ W_h2h, const float* __restrict__ W_hh,
    const float* __restrict__ W_gen, const float* __restrict__ b_ih,
    const float* __restrict__ b_hh, const float* __restrict__ b_h2h,
    u16* __restrict__ bHb, u16* __restrict__ Wi2hb, u16* __restrict__ embb,
    u16* __restrict__ Wctxb, u16* __restrict__ Wceb, u16* __restrict__ Whcatb,
    u16* __restrict__ Wgenb, float* __restrict__ biascat,
    u16* __restrict__ hb, float* __restrict__ cst,
    float* __restrict__ hpbuf, float* __restrict__ ghbuf) {
  const u32 u = blockIdx.x * 256 + threadIdx.x;
  if (u < 2097152u) { conv4(batch_H, bHb, u * 4); return; }
  if (u < 2162688u) { conv4(W_i2h, Wi2hb, (u - 2097152u) * 4); return; }
  if (u < 2586624u) { conv4(emb, embb, (u - 2162688u) * 4); return; }
  if (u < 2588672u) {  // zero emb pad rows 6624..6655
    *(u16x4*)(embb + 1695744u + (u - 2586624u) * 4) = (u16x4){0, 0, 0, 0};
    return;
  }
  if (u < 2850816u) {  // Wctx = W_ih[:, 0:512]
    int i = (u - 2588672u) * 4;
    int r = i >> 9, c = i & 511;
    f32x4 v = *(const f32x4*)(W_ih + (size_t)r * 768 + c);
    u16x4 o;
    o.x = f2bf(v.x); o.y = f2bf(v.y); o.z = f2bf(v.z); o.w = f2bf(v.w);
    *(u16x4*)(Wctxb + i) = o;
    return;
  }
  if (u < 2981888u) {  // Wce = W_ih[:, 512:768]
    int i = (u - 2850816u) * 4;
    int r = i >> 8, c = i & 255;
    f32x4 v = *(const f32x4*)(W_ih + (size_t)r * 768 + 512 + c);
    u16x4 o;
    o.x = f2bf(v.x); o.y = f2bf(v.y); o.z = f2bf(v.z); o.w = f2bf(v.w);
    *(u16x4*)(Wceb + i) = o;
    return;
  }
  if (u < 3309568u) {  // Whcat = [W_h2h ; W_hh], 2560 x 512
    int i = (u - 2981888u) * 4;
    int r = i >> 9, c = i & 511;
    const float* src = (r < 512) ? (W_h2h + (size_t)r * 512 + c)
                                 : (W_hh + (size_t)(r - 512) * 512 + c);
    f32x4 v = *(const f32x4*)src;
    u16x4 o;
    o.x = f2bf(v.x); o.y = f2bf(v.y); o.z = f2bf(v.z); o.w = f2bf(v.w);
    *(u16x4*)(Whcatb + i) = o;
    return;
  }
  if (u < 4161536u) {  // Wgen padded to 6656 rows
    int i = (u - 3309568u) * 4;
    int r = i >> 9;
    if (r < 6624) conv4(W_gen, Wgenb, i);
    else *(u16x4*)(Wgenb + i) = (u16x4){0, 0, 0, 0};
    return;
  }
  if (u < 4162048u) {  // biascat
    int j = (u - 4161536u) * 4;
    f32x4 a = *(const f32x4*)(b_ih + j), b = *(const f32x4*)(b_hh + j);
    f32x4 r = {a.x + b.x, a.y + b.y, a.z + b.z, a.w + b.w};
    *(f32x4*)(biascat + j) = r;
    return;
  }
  if (u < 4178432u) {  // zero hb (h0 = 0), 16B units
    *(u32x4*)((char*)hb + (size_t)(u - 4162048u) * 16) = (u32x4){0, 0, 0, 0};
    return;
  }
  if (u < 4211200u) {  // zero cst
    *(u32x4*)((char*)cst + (size_t)(u - 4178432u) * 16) = (u32x4){0, 0, 0, 0};
    return;
  }
  if (u < 4243968u) {  // hp(0) = b_h2h broadcast (h0 = 0)
    int i = (u - 4211200u) * 4;
    int j = i & 511;
    *(f32x4*)(hpbuf + i) = *(const f32x4*)(b_h2h + j);
    return;
  }
  if (u < 4375040u) {  // gh(0) = 0
    *(u32x4*)((char*)ghbuf + (size_t)(u - 4243968u) * 16) = (u32x4){0, 0, 0, 0};
    return;
  }
}

// ---------------- 128x128x(BK=128) GEMM body: C = A * B^T (+bias) ----------------
// OUT_MODE: 1 = f32 + bias, 2 = bf16 no bias, 3 = bf16 + bias. 4 waves of 64x64.
template <int OUT_MODE>
__device__ __forceinline__ void gemm128_body(
    const u16* __restrict__ A, int lda, const u16* __restrict__ B, int ldb,
    const float* __restrict__ bias, float* __restrict__ Cf, u16* __restrict__ Cb,
    int ldc, int Nreal, int K, int m0, int n0, char* smem) {
  u16* sA = (u16*)smem;            // 128 x 128 = 32 KB
  u16* sB = (u16*)(smem + 32768);  // 128 x 128 = 32 KB
  const int tid = threadIdx.x;
  const int lane = tid & 63, wave = tid >> 6;
  const int wr = wave >> 1, wc = wave & 1;
  const int l15 = lane & 15, lhi = lane >> 4;

  f32x4 acc[4][4];
#pragma unroll
  for (int i = 0; i < 4; ++i)
#pragma unroll
    for (int j = 0; j < 4; ++j) acc[i][j] = 0.f;

  for (int k0 = 0; k0 < K; k0 += 128) {
    __syncthreads();
#pragma unroll
    for (int j = 0; j < 8; ++j) {  // A: 128 rows x 16 chunks
      int idx = j * 256 + tid, row = idx >> 4, cc = idx & 15, c = cc ^ (row & 15);
      gload_lds16(A + (size_t)(m0 + row) * lda + (k0 + c * 8), sA + idx * 8);
    }
#pragma unroll
    for (int j = 0; j < 8; ++j) {  // B: 128 rows x 16 chunks
      int idx = j * 256 + tid, row = idx >> 4, cc = idx & 15, c = cc ^ (row & 15);
      gload_lds16(B + (size_t)(n0 + row) * ldb + (k0 + c * 8), sB + idx * 8);
    }
    __syncthreads();

#pragma unroll
    for (int ks = 0; ks < 4; ++ks) {
      u16x8 av[4], bv[4];
#pragma unroll
      for (int mi = 0; mi < 4; ++mi) {
        int row = wr * 64 + mi * 16 + l15;
        int ch = row * 16 + ((ks * 4 + lhi) ^ (row & 15));
        av[mi] = *(const u16x8*)(sA + ch * 8);
      }
#pragma unroll
      for (int ni = 0; ni < 4; ++ni) {
        int row = wc * 64 + ni * 16 + l15;
        int ch = row * 16 + ((ks * 4 + lhi) ^ (row & 15));
        bv[ni] = *(const u16x8*)(sB + ch * 8);
      }
#pragma unroll
      for (int mi = 0; mi < 4; ++mi)
#pragma unroll
        for (int ni = 0; ni < 4; ++ni) acc[mi][ni] = mfma_bf16(av[mi], bv[ni], acc[mi][ni]);
    }
  }

  asm volatile("s_nop 7\ns_nop 7\ns_nop 7");  // MFMA->VALU hazard guard

#pragma unroll
  for (int mi = 0; mi < 4; ++mi) {
#pragma unroll
    for (int ni = 0; ni < 4; ++ni) {
      int col = n0 + wc * 64 + ni * 16 + l15;
      if (col < Nreal) {
        float bvv = (OUT_MODE == 1 || OUT_MODE == 3) ? bias[col] : 0.f;
#pragma unroll
        for (int r = 0; r < 4; ++r) {
          int row = m0 + wr * 64 + mi * 16 + lhi * 4 + r;
          float v = acc[mi][ni][r] + bvv;
          if (OUT_MODE == 2 || OUT_MODE == 3)
            Cb[(size_t)row * ldc + col] = f2bf(v);
          else
            Cf[(size_t)row * ldc + col] = v;
        }
      }
    }
  }
}

// SWZ: bijective XCD-aware remap (requires gridX*gridY % 8 == 0)
template <int OUT_MODE, bool SWZ>
__global__ __launch_bounds__(256) void kGemm128(const u16* __restrict__ A, int lda,
                                                const u16* __restrict__ B, int ldb,
                                                const float* __restrict__ bias,
                                                float* __restrict__ Cf, u16* __restrict__ Cb,
                                                int ldc, int Nreal, int K) {
  __shared__ __align__(16) char smem[65536];
  int bx = blockIdx.x, by = blockIdx.y;
  if (SWZ) {
    int gx = gridDim.x;
    int lin = by * gx + bx;
    int q = (gx * gridDim.y) >> 3;
    int idx = (lin & 7) * q + (lin >> 3);
    by = idx / gx;
    bx = idx - by * gx;
  }
  gemm128_body<OUT_MODE>(A, lda, B, ldb, bias, Cf, Cb, ldc, Nreal, K,
                         by * 128, bx * 128, smem);
}

// ---------------- kHE: Hproj GEMM + E2G GEMM (bf16 out) in one dispatch ----------------
__global__ __launch_bounds__(256) void kHE(const u16* __restrict__ bHb,
                                           const u16* __restrict__ Wi2hb,
                                           u16* __restrict__ Hproj,
                                           const u16* __restrict__ embb,
                                           const u16* __restrict__ Wceb,
                                           const float* __restrict__ biascat,
                                           u16* __restrict__ E2Gb) {
  __shared__ __align__(16) char smem[65536];
  const int bid = blockIdx.x;
  if (bid < 512) {  // Hproj: M=16384 (128 mt) x N=512 (4 nt), K=512
    gemm128_body<2>(bHb, 512, Wi2hb, 512, nullptr, nullptr, Hproj, 512, 512, 512,
                    (bid >> 2) * 128, (bid & 3) * 128, smem);
  } else {  // E2G: M=6656 (52 mt) x N=2048 (16 nt), K=256 -> bf16 + bias
    int r = bid - 512;
    gemm128_body<3>(embb, 256, Wceb, 256, biascat, nullptr, E2Gb, 2048, 2048, 256,
                    (r >> 4) * 128, (r & 15) * 128, smem);
  }
}

// ---------------- kA: hp + gh GEMM, BM=64 BN=64, single-stage full-K ----------------
// [hp|gh][256, 2560] = h[256,512] @ [W_h2h;W_hh]^T ; hp gets +b_h2h.
// grid 160: b0 = (bid/40)*64, n0 = (bid%40)*64. 128 KB LDS, ONE drain, 16 K-slices.
__global__ __launch_bounds__(256) void kA_hpgh(const u16* __restrict__ hb,
                                               const u16* __restrict__ Whcatb,
                                               const float* __restrict__ b_h2h,
                                               float* __restrict__ hpbuf,
                                               float* __restrict__ ghbuf) {
  extern __shared__ __align__(16) char smem[];
  u16* sA = (u16*)smem;             // 64 x 512 = 64 KB
  u16* sB = (u16*)(smem + 65536);   // 64 x 512 = 64 KB
  const int tid = threadIdx.x;
  const int lane = tid & 63, wave = tid >> 6;  // 4 m-waves of 16 rows (WM=16, WN=64)
  const int l15 = lane & 15, lhi = lane >> 4;
  const int b0 = ((int)blockIdx.x / 40) * 64, n0 = ((int)blockIdx.x % 40) * 64;

#pragma unroll
  for (int j = 0; j < 16; ++j) {  // A: 64 rows x 64 chunks
    int idx = j * 256 + tid, row = idx >> 6, cc = idx & 63, c = cc ^ (row & 15);
    gload_lds16(hb + (size_t)(b0 + row) * 512 + c * 8, sA + idx * 8);
  }
#pragma unroll
  for (int j = 0; j < 16; ++j) {  // B: 64 rows x 64 chunks
    int idx = j * 256 + tid, row = idx >> 6, cc = idx & 63, c = cc ^ (row & 15);
    gload_lds16(Whcatb + (size_t)(n0 + row) * 512 + c * 8, sB + idx * 8);
  }
  __syncthreads();  // single vmcnt drain

  f32x4 acc[4];
#pragma unroll
  for (int j = 0; j < 4; ++j) acc[j] = 0.f;
#pragma unroll
  for (int ks = 0; ks < 16; ++ks) {
    u16x8 av, bv[4];
    {
      int row = wave * 16 + l15;
      int ch = row * 64 + ((ks * 4 + lhi) ^ (row & 15));
      av = *(const u16x8*)(sA + ch * 8);
    }
#pragma unroll
    for (int ni = 0; ni < 4; ++ni) {
      int row = ni * 16 + l15;
      int ch = row * 64 + ((ks * 4 + lhi) ^ (row & 15));
      bv[ni] = *(const u16x8*)(sB + ch * 8);
    }
#pragma unroll
    for (int ni = 0; ni < 4; ++ni) acc[ni] = mfma_bf16(av, bv[ni], acc[ni]);
  }
  asm volatile("s_nop 7\ns_nop 7\ns_nop 7");
#pragma unroll
  for (int ni = 0; ni < 4; ++ni) {
    int col = n0 + ni * 16 + l15;
    int rowg = b0 + wave * 16 + lhi * 4;
    if (col < 512) {
      float bvv = b_h2h[col];
#pragma unroll
      for (int r = 0; r < 4; ++r)
        hpbuf[(size_t)(rowg + r) * 512 + col] = acc[ni][r] + bvv;
    } else {
#pragma unroll
      for (int r = 0; r < 4; ++r)
        ghbuf[(size_t)(rowg + r) * 2048 + col - 512] = acc[ni][r];
    }
  }
}

// ---------------- kB: attention ----------------
__global__ __launch_bounds__(256) void kB_attn(const u16* __restrict__ Hproj,
                                               const float* __restrict__ hpbuf,
                                               const float* __restrict__ wsc,
                                               const u16* __restrict__ bh,
                                               u16* __restrict__ ctxb) {
  const int b = blockIdx.x, tid = threadIdx.x;
  __shared__ float hpsp[528];  // padded: j -> j + (j>>5)
  __shared__ float wssp[528];
  __shared__ float es[64];

  {
    int j0 = tid * 2;
    hpsp[j0 + (j0 >> 5)] = hpbuf[(size_t)b * 512 + j0];
    hpsp[j0 + 1 + ((j0 + 1) >> 5)] = hpbuf[(size_t)b * 512 + j0 + 1];
    int pi = j0 + (j0 >> 5);
    wssp[pi] = wsc[j0];
    wssp[pi + 1] = wsc[j0 + 1];
  }
  __syncthreads();

  const int ch16 = tid & 15;
  const int hbase = ch16 * 33;
  const int hc = ch16 * 32;
  float hpr[32], wsr[32];
#pragma unroll
  for (int j = 0; j < 32; ++j) {
    hpr[j] = hpsp[hbase + j];
    wsr[j] = wssp[hbase + j];
  }
#pragma unroll
  for (int tg = 0; tg < 4; ++tg) {
    int t = tg * 16 + (tid >> 4);
    const u16* hr = Hproj + (size_t)(b * 64 + t) * 512 + hc;
    float s = 0.f;
#pragma unroll
    for (int jo = 0; jo < 32; jo += 8) {
      u16x8 hv = *(const u16x8*)(hr + jo);
#pragma unroll
      for (int j = 0; j < 8; ++j) {
        float x = bf2f(hv[j]) + hpr[jo + j];
        s += fast_tanh(x) * wsr[jo + j];
      }
    }
#pragma unroll
    for (int off = 8; off; off >>= 1) s += __shfl_xor(s, off, 16);
    if (ch16 == 0) es[t] = s;
  }
  __syncthreads();
  if (tid < 64) {  // softmax over t
    float v = es[tid];
    float m = v;
#pragma unroll
    for (int o = 32; o; o >>= 1) m = fmaxf(m, __shfl_xor(m, o, 64));
    float p = __expf(v - m);
    float su = p;
#pragma unroll
    for (int o = 32; o; o >>= 1) su += __shfl_xor(su, o, 64);
    es[tid] = p / su;
  }
  __syncthreads();
  const u16* base = bh + (size_t)b * 32768 + tid * 2;
  float c0 = 0.f, c1 = 0.f;
#pragma unroll 8
  for (int t = 0; t < 64; ++t) {
    u32 w = *(const u32*)(base + t * 512);
    float a = es[t];
    c0 = fmaf(a, bf2f((u16)(w & 0xffffu)), c0);
    c1 = fmaf(a, bf2f((u16)(w >> 16)), c1);
  }
  u32 pk = (u32)f2bf(c0) | ((u32)f2bf(c1) << 16);
  *(u32*)(ctxb + (size_t)b * 512 + tid * 2) = pk;
}

// ---------------- kC: gates_ctx GEMM single-stage full-K + gh + E2G + LSTM ----------------
// grid (32, 8): jj = 16-wide j-tile (4 gate segs -> 64 B-rows), b0 = 32-wide batch tile.
// 256 blocks = 1/CU. LDS 96 KB: A 32x512 (32 KB) + B 64x512 (64 KB).
__global__ __launch_bounds__(256) void kC_gates_lstm(const u16* __restrict__ ctxb,
                                                     const u16* __restrict__ Wctxb,
                                                     const u16* __restrict__ E2Gb,
                                                     const float* __restrict__ ghbuf,
                                                     const int* __restrict__ text,
                                                     float* __restrict__ cst,
                                                     u16* __restrict__ hb,
                                                     u16* __restrict__ hsb, int step) {
  extern __shared__ __align__(16) char smem[];
  u16* sA = (u16*)smem;             // 32 x 512 = 32 KB
  u16* sB = (u16*)(smem + 32768);   // 64 x 512 = 64 KB
  const int tid = threadIdx.x;
  const int lane = tid & 63, wave = tid >> 6;
  const int wr = wave >> 1, wc = wave & 1;  // WM=16 (2 m-waves), WN=32 (2 n-waves)
  const int l15 = lane & 15, lhi = lane >> 4;
  const int jj = blockIdx.x;       // 0..31, 16 j's each
  const int b0 = blockIdx.y * 32;  // 0..7

#pragma unroll
  for (int j = 0; j < 8; ++j) {  // A: 32 rows x 64 chunks
    int idx = j * 256 + tid, row = idx >> 6, cc = idx & 63, c = cc ^ (row & 15);
    gload_lds16(ctxb + (size_t)(b0 + row) * 512 + c * 8, sA + idx * 8);
  }
#pragma unroll
  for (int j = 0; j < 16; ++j) {  // B: 64 rows (4 segs x 16 j) x 64 chunks
    int idx = j * 256 + tid, row = idx >> 6, cc = idx & 63, c = cc ^ (row & 15);
    int grow = (row >> 4) * 512 + jj * 16 + (row & 15);
    gload_lds16(Wctxb + (size_t)grow * 512 + c * 8, sB + idx * 8);
  }
  __syncthreads();  // single vmcnt drain

  f32x4 acc[2];
#pragma unroll
  for (int j = 0; j < 2; ++j) acc[j] = 0.f;
#pragma unroll
  for (int ks = 0; ks < 16; ++ks) {
    u16x8 av, bv[2];
    {
      int row = wr * 16 + l15;
      int ch = row * 64 + ((ks * 4 + lhi) ^ (row & 15));
      av = *(const u16x8*)(sA + ch * 8);
    }
#pragma unroll
    for (int ni = 0; ni < 2; ++ni) {
      int row = wc * 32 + ni * 16 + l15;
      int ch = row * 64 + ((ks * 4 + lhi) ^ (row & 15));
      bv[ni] = *(const u16x8*)(sB + ch * 8);
    }
#pragma unroll
    for (int ni = 0; ni < 2; ++ni) acc[ni] = mfma_bf16(av, bv[ni], acc[ni]);
  }

  asm volatile("s_nop 7\ns_nop 7\ns_nop 7");  // MFMA->VALU hazard guard
  __syncthreads();                            // staging reads done -> reuse LDS
  float (*gsm)[68] = (float(*)[68])smem;      // 32 x 68 f32 = 8.7 KB
#pragma unroll
  for (int ni = 0; ni < 2; ++ni) {
    int col = wc * 32 + ni * 16 + l15;  // col: seg = col>>4, jloc = col&15
    int row = wr * 16 + lhi * 4;
#pragma unroll
    for (int r = 0; r < 4; ++r) gsm[row + r][col] = acc[ni][r];
  }
  __syncthreads();

  {  // LSTM: thread owns bl = tid>>3 (32 b's), 2 j's at jl = (tid&7)*2
    const int bl = tid >> 3, jl = (tid & 7) * 2;
    const int b = b0 + bl;
    const int jg = jj * 16 + jl;  // global j base (2 consecutive)
    const int ci = text[b * 26 + step];
    const float* gh = ghbuf + (size_t)b * 2048;
    const u16* ge = E2Gb + (size_t)ci * 2048;  // bf16, includes biascat
    float cn[2];
    u16 hbv[2];
#pragma unroll
    for (int q = 0; q < 2; ++q) {
      int jc = jl + q, j = jg + q;
      float gi = gsm[bl][jc]      + gh[j]        + bf2f(ge[j]);
      float gf = gsm[bl][16 + jc] + gh[512 + j]  + bf2f(ge[512 + j]);
      float gg = gsm[bl][32 + jc] + gh[1024 + j] + bf2f(ge[1024 + j]);
      float go = gsm[bl][48 + jc] + gh[1536 + j] + bf2f(ge[1536 + j]);
      float c = fast_sig(gf) * cst[(size_t)b * 512 + j] + fast_sig(gi) * fast_tanh(gg);
      cn[q] = c;
      hbv[q] = f2bf(fast_sig(go) * fast_tanh(c));
    }
    *(f32x2*)(cst + (size_t)b * 512 + jg) = *(f32x2*)cn;
    u32 pk = (u32)hbv[0] | ((u32)hbv[1] << 16);
    *(u32*)(hb + (size_t)b * 512 + jg) = pk;
    *(u32*)(hsb + (size_t)(b * 26 + step) * 512 + jg) = pk;
  }
}

// ---------------- launch ----------------
extern "C" void kernel_launch(void* const* d_in, const int* in_sizes, int n_in,
                              void* d_out, int out_size, void* d_ws, size_t ws_size,
                              hipStream_t stream) {
  const float* batch_H = (const float*)d_in[0];
  const int*   text    = (const int*)d_in[1];
  const float* W_i2h   = (const float*)d_in[2];
  const float* W_h2h   = (const float*)d_in[3];
  const float* b_h2h   = (const float*)d_in[4];
  const float* w_score = (const float*)d_in[5];
  const float* W_ih    = (const float*)d_in[6];
  const float* W_hh    = (const float*)d_in[7];
  const float* b_ih    = (const float*)d_in[8];
  const float* b_hh    = (const float*)d_in[9];
  const float* emb     = (const float*)d_in[10];
  const float* W_gen   = (const float*)d_in[11];
  const float* b_gen   = (const float*)d_in[12];
  float* out = (float*)d_out;

  // allow large dynamic LDS for the single-stage step GEMMs (host-side, capture-safe)
  static bool attr_done = []() {
    hipFuncSetAttribute(reinterpret_cast<const void*>(kA_hpgh),
                        hipFuncAttributeMaxDynamicSharedMemorySize, 163840);
    hipFuncSetAttribute(reinterpret_cast<const void*>(kC_gates_lstm),
                        hipFuncAttributeMaxDynamicSharedMemorySize, 163840);
    return true;
  }();
  (void)attr_done;

  // Big bf16 scratch at the front of d_out (fully overwritten by the final GEMM,
  // which reads only hsb/Wgenb; both live in d_ws).
  u16* bHb   = (u16*)d_out;          // 16 MB
  u16* Hproj = bHb + 8388608;        // 16 MB

  char* w = (char*)d_ws;
  auto alloc = [&](size_t bytes) {
    char* p = w;
    w += (bytes + 255) & ~(size_t)255;
    return p;
  };
  u16*   Wi2hb   = (u16*)alloc(512ull * 512 * 2);
  u16*   Whcatb  = (u16*)alloc(2560ull * 512 * 2);   // [W_h2h ; W_hh]
  u16*   Wctxb   = (u16*)alloc(2048ull * 512 * 2);   // W_ih[:, 0:512]
  u16*   Wceb    = (u16*)alloc(2048ull * 256 * 2);   // W_ih[:, 512:768]
  u16*   Wgenb   = (u16*)alloc(6656ull * 512 * 2);
  u16*   embb    = (u16*)alloc(6656ull * 256 * 2);   // padded rows >= 6624
  float* biascat = (float*)alloc(2048ull * 4);
  u16*   ctxb    = (u16*)alloc(256ull * 512 * 2);
  u16*   hb      = (u16*)alloc(256ull * 512 * 2);
  float* cst     = (float*)alloc(256ull * 512 * 4);
  float* hpbuf   = (float*)alloc(256ull * 512 * 4);
  float* ghbuf   = (float*)alloc(256ull * 2048 * 4);
  u16*   hsb     = (u16*)alloc(6656ull * 512 * 2);
  u16*   E2Gb    = (u16*)alloc(6656ull * 2048 * 2);  // bf16: emb@W_ce^T + biascat

  // 1) fused prep (conversions + packing + zero h/c + hp/gh step-0 init)
  k_prep<<<17090, 256, 0, stream>>>(batch_H, W_i2h, emb, W_ih, W_h2h, W_hh, W_gen,
                                    b_ih, b_hh, b_h2h, bHb, Wi2hb, embb, Wctxb, Wceb,
                                    Whcatb, Wgenb, biascat, hb, cst, hpbuf, ghbuf);

  // 2) Hproj + E2G (bf16) in one dispatch
  kHE<<<1344, 256, 0, stream>>>(bHb, Wi2hb, Hproj, embb, Wceb, biascat, E2Gb);

  // 3) recurrence: hp(0)/gh(0) from prep; per step {kA(s>0); kB; kC}
  for (int s = 0; s < 26; ++s) {
    if (s > 0)
      kA_hpgh<<<160, 256, 131072, stream>>>(hb, Whcatb, b_h2h, hpbuf, ghbuf);
    kB_attn<<<256, 256, 0, stream>>>(Hproj, hpbuf, w_score, bHb, ctxb);
    kC_gates_lstm<<<dim3(32, 8), 256, 98304, stream>>>(ctxb, Wctxb, E2Gb, ghbuf, text,
                                                       cst, hb, hsb, s);
  }

  // 4) probs = hs @ W_gen^T + b_gen -> f32 out (M=6656, N=6624, K=512), XCD-swizzled
  kGemm128<1, true><<<dim3(52, 52), 256, 0, stream>>>(
      hsb, 512, Wgenb, 512, b_gen, out, nullptr, 6624, 6624, 512);

  (void)in_sizes; (void)n_in; (void)out_size; (void)ws_size;
}